// Round 6
// baseline (760.967 us; speedup 1.0000x reference)
//
#include <hip/hip_runtime.h>
#include <hip/hip_bf16.h>

static constexpr int N_NODES = 100000;
static constexpr int N_EDGES = 1600000;
static constexpr int N_GRAPH = 2048;
static constexpr float BN_EPS_C = 1e-5f;

typedef unsigned int uint;
typedef unsigned short ushort;

// ---------------- bf16 helpers (RNE pack, shift unpack) ----------------

__device__ inline uint pk2(float a, float b) {
    uint ua = __float_as_uint(a), ub = __float_as_uint(b);
    ua = (ua + 0x7fffu + ((ua >> 16) & 1u)) >> 16;
    ub = (ub + 0x7fffu + ((ub >> 16) & 1u)) >> 16;
    return ua | (ub << 16);
}
__device__ inline float b2f_lo(uint u) { return __uint_as_float(u << 16); }
__device__ inline float b2f_hi(uint u) { return __uint_as_float(u & 0xffff0000u); }

__device__ inline void unpack8(uint4 v, float* f) {
    f[0] = b2f_lo(v.x); f[1] = b2f_hi(v.x);
    f[2] = b2f_lo(v.y); f[3] = b2f_hi(v.y);
    f[4] = b2f_lo(v.z); f[5] = b2f_hi(v.z);
    f[6] = b2f_lo(v.w); f[7] = b2f_hi(v.w);
}

// ---------------- CSR build ----------------
// R5 lesson: device-scope atomics are memory-side RMWs (~32B write each,
// privatization across XCDs changed nothing). So pay the 1.6M atomics ONCE:
// rank pass records each edge's within-row rank; scatter is then atomic-free.

__global__ __launch_bounds__(256) void k_rank(const int* __restrict__ dst, int* __restrict__ deg,
                                              ushort* __restrict__ rank) {
    int i = blockIdx.x * 256 + threadIdx.x;
    if (i < N_EDGES) {
        int d = __builtin_nontemporal_load(&dst[i]);
        int r = atomicAdd(&deg[d], 1);
        rank[i] = (ushort)r;
    }
}

__global__ __launch_bounds__(256) void k_scan_partial(const int* __restrict__ deg, int* __restrict__ part) {
    __shared__ int sw[4];
    int b = blockIdx.x, tid = threadIdx.x;
    int base = b * 1024;
    int s = 0;
#pragma unroll
    for (int r = 0; r < 4; ++r) {
        int i = base + r * 256 + tid;
        if (i < N_NODES) s += deg[i];
    }
#pragma unroll
    for (int off = 32; off > 0; off >>= 1) s += __shfl_down(s, off);
    if ((tid & 63) == 0) sw[tid >> 6] = s;
    __syncthreads();
    if (tid == 0) part[b] = sw[0] + sw[1] + sw[2] + sw[3];
}

__global__ __launch_bounds__(256) void k_scan_offsets(int* __restrict__ part, int nb) {
    __shared__ int sh[256];
    int tid = threadIdx.x;
    sh[tid] = (tid < nb) ? part[tid] : 0;
    __syncthreads();
    if (tid == 0) {
        int run = 0;
        for (int i = 0; i < nb; ++i) { int v = sh[i]; sh[i] = run; run += v; }
    }
    __syncthreads();
    if (tid < nb) part[tid] = sh[tid];
}

__global__ __launch_bounds__(256) void k_scan_final(const int* __restrict__ deg, const int* __restrict__ part,
                                                    int* __restrict__ row_ptr) {
    __shared__ int wsum[4];
    int b = blockIdx.x, tid = threadIdx.x;
    int lane = tid & 63, w = tid >> 6;
    int base = b * 1024 + tid * 4;
    int v[4];
#pragma unroll
    for (int r = 0; r < 4; ++r) {
        int i = base + r;
        v[r] = (i < N_NODES) ? deg[i] : 0;
    }
    int tsum = v[0] + v[1] + v[2] + v[3];
    int inc = tsum;
#pragma unroll
    for (int off = 1; off < 64; off <<= 1) {
        int t = __shfl_up(inc, off);
        if (lane >= off) inc += t;
    }
    if (lane == 63) wsum[w] = inc;
    __syncthreads();
    int woff = 0;
    for (int ww = 0; ww < w; ++ww) woff += wsum[ww];
    int run = part[b] + woff + (inc - tsum);
#pragma unroll
    for (int r = 0; r < 4; ++r) {
        int i = base + r;
        if (i < N_NODES) row_ptr[i] = run;
        run += v[r];
    }
    if (b == 0 && tid == 0) row_ptr[N_NODES] = N_EDGES;
}

// Atomic-free range-partitioned scatter: pos = row_ptr[d] + rank[e].
__global__ __launch_bounds__(256) void k_scatter_nr(const int* __restrict__ src, const int* __restrict__ dst,
                                                    const ushort* __restrict__ rank,
                                                    const int* __restrict__ row_ptr, int* __restrict__ ssrc,
                                                    int lo, int hi) {
    int i = blockIdx.x * 256 + threadIdx.x;
    if (i >= N_EDGES) return;
    int d = __builtin_nontemporal_load(&dst[i]);
    if (d >= lo && d < hi) {
        int s = __builtin_nontemporal_load(&src[i]);
        int r = (int)__builtin_nontemporal_load(&rank[i]);
        ssrc[row_ptr[d] + r] = s;
    }
}

// ---------------- x -> bf16 ----------------

__global__ __launch_bounds__(256) void k_cvt_bf16(const float* __restrict__ x, ushort* __restrict__ xb, int n) {
    int i = (blockIdx.x * 256 + threadIdx.x) * 8;
    if (i >= n) return;
    float4 a = *(const float4*)(x + i);
    float4 b = *(const float4*)(x + i + 4);
    *(uint4*)(xb + i) = make_uint4(pk2(a.x, a.y), pk2(a.z, a.w), pk2(b.x, b.y), pk2(b.z, b.w));
}

// ---------------- fused layer 1: gather(x) + MLP + stats ----------------
// 8 lanes/node cooperative: lane gathers 8 of 64 input feats, computes its
// k-slice of t = relu(agg@Wa+ba), butterfly-shares t within the node-octet,
// then computes 4 of 32 outputs of u = t@Wb+bb. No agg intermediate.

__global__ __launch_bounds__(256) void k_layer1(const ushort* __restrict__ xb,
        const int* __restrict__ row_ptr, const int* __restrict__ row_end,
        const int* __restrict__ ssrc,
        const float* __restrict__ Wa, const float* __restrict__ ba,
        const float* __restrict__ Wb, const float* __restrict__ bb,
        ushort* __restrict__ u, float* __restrict__ stats) {
    __shared__ float sWa[2048];
    __shared__ float sWb[1024];
    __shared__ float sba[32], sbb[32];
    __shared__ float bstats[64];
    int tid = threadIdx.x;
    for (int i = tid; i < 2048; i += 256) sWa[i] = Wa[i];
    for (int i = tid; i < 1024; i += 256) sWb[i] = Wb[i];
    if (tid < 32) { sba[tid] = ba[tid]; sbb[tid] = bb[tid]; }
    if (tid < 64) bstats[tid] = 0.f;
    __syncthreads();

    int idx = blockIdx.x * 256 + tid;
    int node = idx >> 3;
    int lane8 = idx & 7;
    int f8 = lane8 * 8;
    bool active = node < N_NODES;

    float acc[8];
#pragma unroll
    for (int j = 0; j < 8; ++j) acc[j] = 0.f;
    if (active) {
        unpack8(*(const uint4*)(xb + (size_t)node * 64 + f8), acc);
        float v[8];
        int e = row_ptr[node], e1 = row_end[node];
        for (; e + 2 <= e1; e += 2) {
            int s0 = ssrc[e], s1 = ssrc[e + 1];
            uint4 va = *(const uint4*)(xb + (size_t)s0 * 64 + f8);
            uint4 vb = *(const uint4*)(xb + (size_t)s1 * 64 + f8);
            unpack8(va, v);
#pragma unroll
            for (int j = 0; j < 8; ++j) acc[j] += v[j];
            unpack8(vb, v);
#pragma unroll
            for (int j = 0; j < 8; ++j) acc[j] += v[j];
        }
        if (e < e1) {
            int s = ssrc[e];
            unpack8(*(const uint4*)(xb + (size_t)s * 64 + f8), v);
#pragma unroll
            for (int j = 0; j < 8; ++j) acc[j] += v[j];
        }
    }

    // phase A partial: t_part = acc(k-slice) @ Wa
    float t[32];
#pragma unroll
    for (int j = 0; j < 32; ++j) t[j] = 0.f;
#pragma unroll
    for (int kk = 0; kk < 8; ++kk) {
        float a = acc[kk];
        const float4* wr = (const float4*)(sWa + (size_t)(f8 + kk) * 32);
#pragma unroll
        for (int j4 = 0; j4 < 8; ++j4) {
            float4 wv = wr[j4];
            t[j4 * 4 + 0] = fmaf(a, wv.x, t[j4 * 4 + 0]);
            t[j4 * 4 + 1] = fmaf(a, wv.y, t[j4 * 4 + 1]);
            t[j4 * 4 + 2] = fmaf(a, wv.z, t[j4 * 4 + 2]);
            t[j4 * 4 + 3] = fmaf(a, wv.w, t[j4 * 4 + 3]);
        }
    }
    // butterfly across the 8 lanes of this node, then bias+relu
#pragma unroll
    for (int j = 0; j < 32; ++j) {
        t[j] += __shfl_xor(t[j], 1);
        t[j] += __shfl_xor(t[j], 2);
        t[j] += __shfl_xor(t[j], 4);
        t[j] = fmaxf(t[j] + sba[j], 0.f);
    }
    // phase B: 4 outputs per lane
    int jb = lane8 * 4;
    float uu[4];
#pragma unroll
    for (int j = 0; j < 4; ++j) uu[j] = sbb[jb + j];
#pragma unroll 4
    for (int k = 0; k < 32; ++k) {
        float4 wv = *(const float4*)(sWb + k * 32 + jb);
        uu[0] = fmaf(t[k], wv.x, uu[0]);
        uu[1] = fmaf(t[k], wv.y, uu[1]);
        uu[2] = fmaf(t[k], wv.z, uu[2]);
        uu[3] = fmaf(t[k], wv.w, uu[3]);
    }
    if (active) {
        uint2 pk = make_uint2(pk2(uu[0], uu[1]), pk2(uu[2], uu[3]));
        *(uint2*)(u + (size_t)node * 32 + jb) = pk;
    } else {
#pragma unroll
        for (int j = 0; j < 4; ++j) uu[j] = 0.f;
    }
    // stats: reduce across the 8 node-octets in the wave
#pragma unroll
    for (int j = 0; j < 4; ++j) {
        float v = uu[j], v2 = v * v;
        v += __shfl_down(v, 32); v2 += __shfl_down(v2, 32);
        v += __shfl_down(v, 16); v2 += __shfl_down(v2, 16);
        v += __shfl_down(v, 8);  v2 += __shfl_down(v2, 8);
        if ((tid & 63) < 8) {
            atomicAdd(&bstats[jb + j], v);
            atomicAdd(&bstats[32 + jb + j], v2);
        }
    }
    __syncthreads();
    if (tid < 64) atomicAdd(&stats[tid], bstats[tid]);
}

// ---------------- fused layers 2-5: BN+ReLU gather + MLP + stats ----------------
// 4 lanes/node: lane gathers+normalizes 8 of 32 feats, k-slice matvec,
// butterfly within quad, 8 outputs per lane.

__global__ __launch_bounds__(256) void k_layer(const ushort* __restrict__ u,
        const int* __restrict__ row_ptr, const int* __restrict__ row_end,
        const int* __restrict__ ssrc,
        const float* __restrict__ stats_in, const float* __restrict__ bng, const float* __restrict__ bnb,
        const float* __restrict__ Wa, const float* __restrict__ ba,
        const float* __restrict__ Wb, const float* __restrict__ bb,
        ushort* __restrict__ u_out, float* __restrict__ stats_out) {
    __shared__ float sWa[1024];
    __shared__ float sWb[1024];
    __shared__ float sba[32], sbb[32], ssc[32], ssh[32];
    __shared__ float bstats[64];
    int tid = threadIdx.x;
    for (int i = tid; i < 1024; i += 256) { sWa[i] = Wa[i]; sWb[i] = Wb[i]; }
    if (tid < 32) {
        sba[tid] = ba[tid]; sbb[tid] = bb[tid];
        const float inv = 1.0f / (float)N_NODES;
        float mu = stats_in[tid] * inv;
        float sc = rsqrtf(stats_in[32 + tid] * inv - mu * mu + BN_EPS_C) * bng[tid];
        ssc[tid] = sc;
        ssh[tid] = bnb[tid] - mu * sc;
    }
    if (tid < 64) bstats[tid] = 0.f;
    __syncthreads();

    int idx = blockIdx.x * 256 + tid;
    int node = idx >> 2;
    int lane4 = idx & 3;
    int f8 = lane4 * 8;
    bool active = node < N_NODES;

    float sc[8], sh[8];
#pragma unroll
    for (int j = 0; j < 8; ++j) { sc[j] = ssc[f8 + j]; sh[j] = ssh[f8 + j]; }

    float acc[8];
#pragma unroll
    for (int j = 0; j < 8; ++j) acc[j] = 0.f;
    if (active) {
        float v[8];
        unpack8(*(const uint4*)(u + (size_t)node * 32 + f8), v);
#pragma unroll
        for (int j = 0; j < 8; ++j) acc[j] = fmaxf(fmaf(v[j], sc[j], sh[j]), 0.f);
        int e = row_ptr[node], e1 = row_end[node];
        for (; e + 2 <= e1; e += 2) {
            int s0 = ssrc[e], s1 = ssrc[e + 1];
            uint4 va = *(const uint4*)(u + (size_t)s0 * 32 + f8);
            uint4 vb = *(const uint4*)(u + (size_t)s1 * 32 + f8);
            unpack8(va, v);
#pragma unroll
            for (int j = 0; j < 8; ++j) acc[j] += fmaxf(fmaf(v[j], sc[j], sh[j]), 0.f);
            unpack8(vb, v);
#pragma unroll
            for (int j = 0; j < 8; ++j) acc[j] += fmaxf(fmaf(v[j], sc[j], sh[j]), 0.f);
        }
        if (e < e1) {
            int s = ssrc[e];
            unpack8(*(const uint4*)(u + (size_t)s * 32 + f8), v);
#pragma unroll
            for (int j = 0; j < 8; ++j) acc[j] += fmaxf(fmaf(v[j], sc[j], sh[j]), 0.f);
        }
    }

    float t[32];
#pragma unroll
    for (int j = 0; j < 32; ++j) t[j] = 0.f;
#pragma unroll
    for (int kk = 0; kk < 8; ++kk) {
        float a = acc[kk];
        const float4* wr = (const float4*)(sWa + (size_t)(f8 + kk) * 32);
#pragma unroll
        for (int j4 = 0; j4 < 8; ++j4) {
            float4 wv = wr[j4];
            t[j4 * 4 + 0] = fmaf(a, wv.x, t[j4 * 4 + 0]);
            t[j4 * 4 + 1] = fmaf(a, wv.y, t[j4 * 4 + 1]);
            t[j4 * 4 + 2] = fmaf(a, wv.z, t[j4 * 4 + 2]);
            t[j4 * 4 + 3] = fmaf(a, wv.w, t[j4 * 4 + 3]);
        }
    }
#pragma unroll
    for (int j = 0; j < 32; ++j) {
        t[j] += __shfl_xor(t[j], 1);
        t[j] += __shfl_xor(t[j], 2);
        t[j] = fmaxf(t[j] + sba[j], 0.f);
    }
    // phase B: 8 outputs per lane at f8
    float uu[8];
#pragma unroll
    for (int j = 0; j < 8; ++j) uu[j] = sbb[f8 + j];
#pragma unroll 4
    for (int k = 0; k < 32; ++k) {
        float a = t[k];
        const float4* wr = (const float4*)(sWb + k * 32 + f8);
        float4 w0 = wr[0], w1 = wr[1];
        uu[0] = fmaf(a, w0.x, uu[0]);
        uu[1] = fmaf(a, w0.y, uu[1]);
        uu[2] = fmaf(a, w0.z, uu[2]);
        uu[3] = fmaf(a, w0.w, uu[3]);
        uu[4] = fmaf(a, w1.x, uu[4]);
        uu[5] = fmaf(a, w1.y, uu[5]);
        uu[6] = fmaf(a, w1.z, uu[6]);
        uu[7] = fmaf(a, w1.w, uu[7]);
    }
    if (active) {
        uint4 pk = make_uint4(pk2(uu[0], uu[1]), pk2(uu[2], uu[3]), pk2(uu[4], uu[5]), pk2(uu[6], uu[7]));
        *(uint4*)(u_out + (size_t)node * 32 + f8) = pk;
    } else {
#pragma unroll
        for (int j = 0; j < 8; ++j) uu[j] = 0.f;
    }
#pragma unroll
    for (int j = 0; j < 8; ++j) {
        float v = uu[j], v2 = v * v;
        v += __shfl_down(v, 32); v2 += __shfl_down(v2, 32);
        v += __shfl_down(v, 16); v2 += __shfl_down(v2, 16);
        v += __shfl_down(v, 8);  v2 += __shfl_down(v2, 8);
        v += __shfl_down(v, 4);  v2 += __shfl_down(v2, 4);
        if ((tid & 63) < 4) {
            atomicAdd(&bstats[f8 + j], v);
            atomicAdd(&bstats[32 + f8 + j], v2);
        }
    }
    __syncthreads();
    if (tid < 64) atomicAdd(&stats_out[tid], bstats[tid]);
}

// ---------------- layer-5 BN + graph pooling (segmented over sorted batch) ----------------

__global__ __launch_bounds__(256) void k_bn_pool(const ushort* __restrict__ u, const float* __restrict__ stats,
                                                 const float* __restrict__ bng, const float* __restrict__ bnb,
                                                 const int* __restrict__ batch, float* __restrict__ pooled) {
    const int CH = 128;
    int wid = (blockIdx.x * 256 + threadIdx.x) >> 6;
    int lane = threadIdx.x & 63;
    int f = lane & 31, par = lane >> 5;
    int n0 = wid * CH;
    if (n0 >= N_NODES) return;
    int n1 = n0 + CH; if (n1 > N_NODES) n1 = N_NODES;
    const float inv = 1.0f / (float)N_NODES;
    float mu = stats[f] * inv;
    float var = stats[32 + f] * inv - mu * mu;
    float sc = rsqrtf(var + BN_EPS_C) * bng[f];
    float sh = bnb[f] - mu * sc;
    float acc = 0.f;
    int curg = -1;
    for (int n = n0 + par; n < n1; n += 2) {
        int g = batch[n];
        if (g != curg) {
            if (curg >= 0) atomicAdd(&pooled[(size_t)curg * 32 + f], acc);
            acc = 0.f; curg = g;
        }
        float v = b2f_lo((uint)u[(size_t)n * 32 + f]);
        acc += fmaxf(fmaf(v, sc, sh), 0.f);
    }
    if (curg >= 0) atomicAdd(&pooled[(size_t)curg * 32 + f], acc);
}

// ---------------- head GEMMs ----------------

#define GEMM_COMPUTE_16()                                                      \
    _Pragma("unroll")                                                          \
    for (int k = 0; k < 16; ++k) {                                             \
        float4 a4 = *(const float4*)&As[k][ty * 4];                            \
        float4 b4 = *(const float4*)&Bs[k][tx * 4];                            \
        acc[0][0] = fmaf(a4.x, b4.x, acc[0][0]);                               \
        acc[0][1] = fmaf(a4.x, b4.y, acc[0][1]);                               \
        acc[0][2] = fmaf(a4.x, b4.z, acc[0][2]);                               \
        acc[0][3] = fmaf(a4.x, b4.w, acc[0][3]);                               \
        acc[1][0] = fmaf(a4.y, b4.x, acc[1][0]);                               \
        acc[1][1] = fmaf(a4.y, b4.y, acc[1][1]);                               \
        acc[1][2] = fmaf(a4.y, b4.z, acc[1][2]);                               \
        acc[1][3] = fmaf(a4.y, b4.w, acc[1][3]);                               \
        acc[2][0] = fmaf(a4.z, b4.x, acc[2][0]);                               \
        acc[2][1] = fmaf(a4.z, b4.y, acc[2][1]);                               \
        acc[2][2] = fmaf(a4.z, b4.z, acc[2][2]);                               \
        acc[2][3] = fmaf(a4.z, b4.w, acc[2][3]);                               \
        acc[3][0] = fmaf(a4.w, b4.x, acc[3][0]);                               \
        acc[3][1] = fmaf(a4.w, b4.y, acc[3][1]);                               \
        acc[3][2] = fmaf(a4.w, b4.z, acc[3][2]);                               \
        acc[3][3] = fmaf(a4.w, b4.w, acc[3][3]);                               \
    }

__global__ __launch_bounds__(256) void k_gemm_f(const float* __restrict__ A, const float* __restrict__ B,
                                                const float* __restrict__ bias, float* __restrict__ C,
                                                int Nc, int K, int ldc, int do_relu) {
    __shared__ float As[16][64];
    __shared__ float Bs[16][64];
    int tid = threadIdx.x;
    int tx = tid & 15, ty = tid >> 4;
    int bm = blockIdx.x * 64, bn = blockIdx.y * 64;
    float acc[4][4] = {{0.f}};
    int am = tid >> 2;
    int ak = (tid & 3) * 4;
    int bk = tid >> 4;
    int bn4 = (tid & 15) * 4;
    const float* Ap = A + (size_t)(bm + am) * K + ak;
    const float* Bp = B + (size_t)bk * Nc + bn + bn4;
    float4 av = *(const float4*)Ap;
    float4 bv = *(const float4*)Bp;
    for (int k0 = 0; k0 < K; k0 += 16) {
        As[ak + 0][am] = av.x;
        As[ak + 1][am] = av.y;
        As[ak + 2][am] = av.z;
        As[ak + 3][am] = av.w;
        *(float4*)&Bs[bk][bn4] = bv;
        __syncthreads();
        if (k0 + 16 < K) {
            av = *(const float4*)(Ap + k0 + 16);
            bv = *(const float4*)(Bp + (size_t)(k0 + 16) * Nc);
        }
        GEMM_COMPUTE_16()
        __syncthreads();
    }
    float4 bi = *(const float4*)(bias + bn + tx * 4);
#pragma unroll
    for (int i = 0; i < 4; ++i) {
        float4 v;
        v.x = acc[i][0] + bi.x;
        v.y = acc[i][1] + bi.y;
        v.z = acc[i][2] + bi.z;
        v.w = acc[i][3] + bi.w;
        if (do_relu) {
            v.x = fmaxf(v.x, 0.f); v.y = fmaxf(v.y, 0.f);
            v.z = fmaxf(v.z, 0.f); v.w = fmaxf(v.w, 0.f);
        }
        *(float4*)(C + (size_t)(bm + ty * 4 + i) * ldc + bn + tx * 4) = v;
    }
}

__global__ __launch_bounds__(256) void k_gemm_p(const float* __restrict__ A, const float* __restrict__ B,
                                                float* __restrict__ psum, int Nc, int Ktot, int klen) {
    __shared__ float As[16][64];
    __shared__ float Bs[16][64];
    int tid = threadIdx.x;
    int tx = tid & 15, ty = tid >> 4;
    int bm = blockIdx.x * 64, bn = blockIdx.y * 64;
    int kb = blockIdx.z * klen;
    float acc[4][4] = {{0.f}};
    int am = tid >> 2;
    int ak = (tid & 3) * 4;
    int bk = tid >> 4;
    int bn4 = (tid & 15) * 4;
    const float* Ap = A + (size_t)(bm + am) * Ktot + kb + ak;
    const float* Bp = B + (size_t)(kb + bk) * Nc + bn + bn4;
    float4 av = *(const float4*)Ap;
    float4 bv = *(const float4*)Bp;
    for (int k0 = 0; k0 < klen; k0 += 16) {
        As[ak + 0][am] = av.x;
        As[ak + 1][am] = av.y;
        As[ak + 2][am] = av.z;
        As[ak + 3][am] = av.w;
        *(float4*)&Bs[bk][bn4] = bv;
        __syncthreads();
        if (k0 + 16 < klen) {
            av = *(const float4*)(Ap + k0 + 16);
            bv = *(const float4*)(Bp + (size_t)(k0 + 16) * Nc);
        }
        GEMM_COMPUTE_16()
        __syncthreads();
    }
    float* out = psum + (size_t)blockIdx.z * N_GRAPH * Nc;
#pragma unroll
    for (int i = 0; i < 4; ++i) {
        float4 v = make_float4(acc[i][0], acc[i][1], acc[i][2], acc[i][3]);
        *(float4*)(out + (size_t)(bm + ty * 4 + i) * Nc + bn + tx * 4) = v;
    }
}

__global__ __launch_bounds__(256) void k_reduce(const float* __restrict__ psum, const float* __restrict__ bias,
                                                float* __restrict__ C, int S, int Nc, int ldc, int do_relu) {
    int idx = blockIdx.x * 256 + threadIdx.x;
    int nq = Nc >> 2;
    if (idx >= N_GRAPH * nq) return;
    int m = idx / nq;
    int j = (idx - m * nq) * 4;
    float4 s = *(const float4*)(psum + (size_t)m * Nc + j);
    for (int z = 1; z < S; ++z) {
        float4 t = *(const float4*)(psum + (size_t)z * N_GRAPH * Nc + (size_t)m * Nc + j);
        s.x += t.x; s.y += t.y; s.z += t.z; s.w += t.w;
    }
    float4 bi = *(const float4*)(bias + j);
    s.x += bi.x; s.y += bi.y; s.z += bi.z; s.w += bi.w;
    if (do_relu) {
        s.x = fmaxf(s.x, 0.f); s.y = fmaxf(s.y, 0.f);
        s.z = fmaxf(s.z, 0.f); s.w = fmaxf(s.w, 0.f);
    }
    *(float4*)(C + (size_t)m * ldc + j) = s;
}

// ---------------- final dot ----------------

__global__ __launch_bounds__(256) void k_out(const float* __restrict__ z2, const float* __restrict__ w,
                                             const float* __restrict__ b, float* __restrict__ out) {
    int gid = blockIdx.x * 256 + threadIdx.x;
    int g = gid >> 6;
    int lane = threadIdx.x & 63;
    if (g >= N_GRAPH) return;
    float4 a = *(const float4*)(z2 + (size_t)g * 256 + lane * 4);
    float4 wv = *(const float4*)(w + lane * 4);
    float v = a.x * wv.x + a.y * wv.y + a.z * wv.z + a.w * wv.w;
#pragma unroll
    for (int off = 32; off > 0; off >>= 1) v += __shfl_down(v, off);
    if (lane == 0) out[g] = v + b[0];
}

// ---------------- launcher ----------------

extern "C" void kernel_launch(void* const* d_in, const int* in_sizes, int n_in,
                              void* d_out, int out_size, void* d_ws, size_t ws_size,
                              hipStream_t stream) {
    const float* x     = (const float*)d_in[0];
    const int*   eidx  = (const int*)d_in[1];
    const int*   batch = (const int*)d_in[2];
    const float* sf    = (const float*)d_in[3];
    const float* w1a   = (const float*)d_in[4];
    const float* b1a   = (const float*)d_in[5];
    const float* ws_a  = (const float*)d_in[6];
    const float* bs_a  = (const float*)d_in[7];
    const float* ws_b  = (const float*)d_in[8];
    const float* bs_b  = (const float*)d_in[9];
    const float* bn_g  = (const float*)d_in[10];
    const float* bn_b  = (const float*)d_in[11];
    const float* fcg_w = (const float*)d_in[12];
    const float* fcg_b = (const float*)d_in[13];
    const float* fs1_w = (const float*)d_in[14];
    const float* fs1_b = (const float*)d_in[15];
    const float* fs2_w = (const float*)d_in[16];
    const float* fs2_b = (const float*)d_in[17];
    const float* fc1_w = (const float*)d_in[18];
    const float* fc1_b = (const float*)d_in[19];
    const float* fc2_w = (const float*)d_in[20];
    const float* fc2_b = (const float*)d_in[21];
    const float* out_w = (const float*)d_in[22];
    const float* out_b = (const float*)d_in[23];
    float* dout = (float*)d_out;

    // workspace (~44 MB total; fits the R1-proven 46+ MB budget)
    char* p = (char*)d_ws;
    float*  zcat    = (float*)p;  p += (size_t)N_GRAPH * 256 * 4;   // 2 MB  [gfeat | s2]
    float*  s1buf   = (float*)p;  p += (size_t)N_GRAPH * 256 * 4;   // 2 MB
    float*  z2buf   = (float*)p;  p += (size_t)N_GRAPH * 256 * 4;   // 2 MB
    float*  z1buf   = (float*)p;  p += (size_t)N_GRAPH * 1024 * 4;  // 8 MB
    ushort* ubuf    = (ushort*)p; p += (size_t)N_NODES * 32 * 2;    // 6.4 MB
    int*    ssrc    = (int*)p;    p += (size_t)N_EDGES * 4;         // 6.4 MB
    ushort* rank    = (ushort*)p; p += (size_t)N_EDGES * 2;         // 3.2 MB
    int*    row_ptr = (int*)p;    p += (size_t)(N_NODES + 4) * 4;
    int*    part    = (int*)p;    p += 512 * 4;
    int*    deg     = (int*)p;    p += (size_t)N_NODES * 4;         // zero start
    float*  stats   = (float*)p;  p += 320 * 4;
    float*  pooled  = (float*)p;  p += (size_t)N_GRAPH * 32 * 4;    // zero end
    ushort* xb      = (ushort*)p; p += (size_t)N_NODES * 64 * 2;    // 12.8 MB
    (void)ws_size;
    float* psA = z1buf;   // fs1/fs2 partials (dead before fc1 writes z1buf)
    float* psB = zcat;    // fc2 partials: 4 MB spanning zcat+s1buf (both dead by then)

    hipMemsetAsync(deg, 0, ((size_t)N_NODES + 320 + (size_t)N_GRAPH * 32) * 4, stream);

    const int* esrc = eidx;
    const int* edst = eidx + N_EDGES;
    int nb = (N_NODES + 1023) / 1024;  // 98

    // CSR build: one atomic pass (deg + per-edge rank), scan, atomic-free scatter
    k_rank<<<(N_EDGES + 255) / 256, 256, 0, stream>>>(edst, deg, rank);
    k_scan_partial<<<nb, 256, 0, stream>>>(deg, part);
    k_scan_offsets<<<1, 256, 0, stream>>>(part, nb);
    k_scan_final<<<nb, 256, 0, stream>>>(deg, part, row_ptr);
    for (int k = 0; k < 5; ++k) {
        int lo = k * 20000;
        int hi = (k == 4) ? N_NODES : lo + 20000;
        k_scatter_nr<<<(N_EDGES + 255) / 256, 256, 0, stream>>>(esrc, edst, rank, row_ptr, ssrc, lo, hi);
    }

    // fused GIN layers
    k_cvt_bf16<<<(N_NODES * 64 / 8 + 255) / 256, 256, 0, stream>>>(x, xb, N_NODES * 64);
    k_layer1<<<(N_NODES * 8 + 255) / 256, 256, 0, stream>>>(
        xb, row_ptr, row_ptr + 1, ssrc, w1a, b1a, ws_b, bs_b, ubuf, stats);
    for (int L = 1; L <= 4; ++L) {
        k_layer<<<(N_NODES * 4 + 255) / 256, 256, 0, stream>>>(
            ubuf, row_ptr, row_ptr + 1, ssrc,
            stats + (L - 1) * 64, bn_g + (L - 1) * 32, bn_b + (L - 1) * 32,
            ws_a + (size_t)(L - 1) * 1024, bs_a + (L - 1) * 32,
            ws_b + (size_t)L * 1024, bs_b + L * 32,
            ubuf, stats + L * 64);
    }
    {
        int waves = (N_NODES + 127) / 128;
        int blocks = (waves + 3) / 4;
        k_bn_pool<<<blocks, 256, 0, stream>>>(ubuf, stats + 256, bn_g + 128, bn_b + 128, batch, pooled);
    }

    // head
    k_gemm_f<<<dim3(32, 2), 256, 0, stream>>>(pooled, fcg_w, fcg_b, zcat, 128, 32, 256, 1);     // -> z[:, :128]
    k_gemm_p<<<dim3(32, 4, 4), 256, 0, stream>>>(sf, fs1_w, psA, 256, 512, 128);                // fs1
    k_reduce<<<512, 256, 0, stream>>>(psA, fs1_b, s1buf, 4, 256, 256, 1);
    k_gemm_p<<<dim3(32, 2, 4), 256, 0, stream>>>(s1buf, fs2_w, psA, 128, 256, 64);              // fs2
    k_reduce<<<256, 256, 0, stream>>>(psA, fs2_b, zcat + 128, 4, 128, 256, 1);                  // -> z[:, 128:]
    k_gemm_f<<<dim3(32, 16), 256, 0, stream>>>(zcat, fc1_w, fc1_b, z1buf, 1024, 256, 1024, 1);  // fc1
    k_gemm_p<<<dim3(32, 4, 2), 256, 0, stream>>>(z1buf, fc2_w, psB, 256, 1024, 512);            // fc2 (S=2)
    k_reduce<<<512, 256, 0, stream>>>(psB, fc2_b, z2buf, 2, 256, 256, 1);
    k_out<<<512, 256, 0, stream>>>(z2buf, out_w, out_b, dout);
}